// Round 18
// baseline (21433.635 us; speedup 1.0000x reference)
//
#include <hip/hip_runtime.h>
#include <hip/hip_bf16.h>

// ---------------- problem constants ----------------
#define NPG   2000
#define BSZ   32
#define NTOT  64000
#define TDIM  256
#define HD    128
#define G4    512
#define MB    16
#define BPG   125
#define NBLK  4000

#define LOG2E      1.44269504088896340736f
#define TWO_LOG2E  2.88539008177792681472f

typedef float  f32x4 __attribute__((ext_vector_type(4)));
typedef short  s16x8 __attribute__((ext_vector_type(8)));
typedef unsigned int u32x2 __attribute__((ext_vector_type(2)));
typedef unsigned short u16;

__device__ __forceinline__ u16 f2bf(float x) {   // round-nearest-even
    unsigned u = __float_as_uint(x);
    return (u16)((u + 0x7FFFu + ((u >> 16) & 1u)) >> 16);
}
// packed f32x2 -> bf16x2 (RNE), single HW instruction
__device__ __forceinline__ unsigned cvt_pk_bf16(float lo, float hi) {
    unsigned r;
    asm("v_cvt_pk_bf16_f32 %0, %1, %2" : "=v"(r) : "v"(lo), "v"(hi));
    return r;
}
__device__ __forceinline__ float fastrcp(float x) { return __builtin_amdgcn_rcpf(x); }
// raw 2^x through a COMPILER-VISIBLE intrinsic (hazard waits inserted properly).
#if __has_builtin(__builtin_amdgcn_exp2f)
__device__ __forceinline__ float ex2(float x) { return __builtin_amdgcn_exp2f(x); }
#else
__device__ __forceinline__ float ex2(float x) { return exp2f(x); }
#endif
// Gate pre-activations are pre-scaled at precompute time:
//   sigmoid rows (g in {0,1,3}): y = -log2e * x  -> sigm = rcp(1 + 2^y)
//   tanh rows    (g == 2):       y = 2log2e * x  -> tanh = 1 - 2*rcp(2^y + 1)
__device__ __forceinline__ float sigmP(float y) { return fastrcp(1.0f + ex2(y)); }
__device__ __forceinline__ float tanhP(float y) { return 1.0f - 2.0f * fastrcp(ex2(y) + 1.0f); }
__device__ __forceinline__ float tanhC(float c) { return tanhP(c * TWO_LOG2E); }   // c in true units

// async global->LDS DMA, 4B per lane, lds dest = uniform base + lane*4
__device__ __forceinline__ void gload_lds4(const float* g, float* l) {
    __builtin_amdgcn_global_load_lds(
        (const __attribute__((address_space(1))) void*)g,
        (__attribute__((address_space(3))) void*)l, 4, 0, 0);
}

// ---- permutations (R5-verified) ----
// gate-col interleave: col' = h*4 + g        (orig gate col = g*128 + h)
// OPERAND-SWAPPED MFMA: D = A(W) x B(h) -> D[col'][node]
//   lane (lrow, lk), acc[nt]: node = lrow, col' = (wave*4+nt)*16 + lk*4 + r
//   => reg r IS the gate index g; h = wave*16 + nt*4 + lk. No transpose needed.
// h-state slot perm16: slot = w*16 + l*4 + n <-> physical h = w*16 + n*4 + l
// GATE PRESCALE: rows g==2 scaled by +2log2e; rows g in {0,1,3} by -log2e.
// anode addend: LOOP-INVARIANT per lane -> held in 16 VGPRs (lds_an deleted, LDS 102->70KiB
//   so a second block can co-reside per CU and fill barrier stalls).
// LDS swizzle: 16-way ((row&15)<<4) on h-state/wd1; lds_d1 keeps 8-way (128B rows).

// ---------------- ws layout (float offsets) ----------------
#define OFF_M2    0
#define OFF_SHE0  4096
#define OFF_XN    8192
#define OFF_S0    8200192
#define OFF_S1    12394496
#define OFF_AN    16588800

// ============== precompute: M2[j][col] = sum_h W_enc[h][j] * W_ih0[col][h] ==============
__global__ void k_m2(const float* __restrict__ Wenc, const float* __restrict__ Wih,
                     float* __restrict__ M2) {
    int col = threadIdx.x;  // 512
    float acc[6];
#pragma unroll
    for (int j = 0; j < 6; j++) acc[j] = 0.f;
    for (int h = 0; h < 128; h++) {
        float wv = Wih[col * 128 + h];
#pragma unroll
        for (int j = 0; j < 6; j++) acc[j] += Wenc[h * 137 + j] * wv;
    }
#pragma unroll
    for (int j = 0; j < 6; j++) M2[j * 512 + col] = acc[j];
}

// ============== precompute: anode[blk][node r][col'] (gate-col permuted, prescaled) ==============
__global__ void k_anode(const float* __restrict__ node, const float* __restrict__ M2,
                        float* __restrict__ anode) {
    int blk = blockIdx.x;
    int col = threadIdx.x;  // 512 (orig col = g*128+h)
    float m[6];
#pragma unroll
    for (int j = 0; j < 6; j++) m[j] = M2[j * 512 + col];
    int g = col >> 7;
    float scl = (g == 2) ? TWO_LOG2E : -LOG2E;
    int colp = (col & 127) * 4 + g;                // col' = h*4 + g
    float* dst = anode + (size_t)blk * 8192 + colp;
#pragma unroll
    for (int r = 0; r < 16; r++) {
        const float* np = node + (size_t)(blk * MB + r) * 6;
        float a = 0.f;
#pragma unroll
        for (int j = 0; j < 6; j++) a += np[j] * m[j];
        dst[r * 512] = a * scl;
    }
}

// ============== precompute: xn[n][h] = sum_j node[n][j] * W_enc[h][j] ==============
__global__ void k_xn(const float* __restrict__ node, const float* __restrict__ Wenc,
                     float* __restrict__ xn) {
    int blk = blockIdx.x;             // 4000
    int h = threadIdx.x & 127;
    int rr = threadIdx.x >> 7;        // 0..3
#pragma unroll
    for (int i = 0; i < 4; i++) {
        int r = rr + i * 4;
        int n = blk * MB + r;
        float a = 0.f;
#pragma unroll
        for (int j = 0; j < 6; j++) a += node[(size_t)n * 6 + j] * Wenc[h * 137 + j];
        xn[(size_t)n * 128 + h] = a;
    }
}

// ============== precompute: shared per-(b,t) terms S0, S1 (col' order, prescaled), shE0 ==============
__global__ void k_shared(const float* __restrict__ lat, const float* __restrict__ gms,
                         const float* __restrict__ Wenc, const float* __restrict__ benc,
                         const float* __restrict__ Wih, const float* __restrict__ bih,
                         const float* __restrict__ bhh,
                         float* __restrict__ S0, float* __restrict__ S1,
                         float* __restrict__ shE0) {
    int bt = blockIdx.x;             // 8192
    int b = bt >> 8, tt = bt & 255;
    __shared__ float she[128];
    int t = threadIdx.x;             // 256
    const float* latp = lat + (size_t)(b * 256 + tt) * 128;
    const float* gp = gms + (size_t)(b * 256 + tt) * 3;
    float g0 = gp[0], g1 = gp[1], g2 = gp[2];
    if (t < 128) {
        float a = benc[t];
        const float* we = Wenc + t * 137;
        for (int i = 0; i < 128; i++) a += latp[i] * we[6 + i];
        a += g0 * we[134] + g1 * we[135] + g2 * we[136];
        she[t] = a;
        if (tt == 0) shE0[b * 128 + t] = a;
    }
    __syncthreads();
    for (int col = t; col < 512; col += 256) {
        float a = bih[col] + bhh[col];
        const float* wr = Wih + col * 128;
        for (int h = 0; h < 128; h++) a += she[h] * wr[h];
        int g = col >> 7;
        float scl = (g == 2) ? TWO_LOG2E : -LOG2E;
        int colp = (col & 127) * 4 + g;            // col' = h*4 + g
        S0[(size_t)(b * 256 + tt) * 512 + colp] = a * scl;
        const float* w1 = Wih + 65536 + col * 128;
        float s1 = bih[512 + col] + bhh[512 + col] + g0 * w1[125] + g1 * w1[126] + g2 * w1[127];
        S1[(size_t)(b * 256 + tt) * 512 + colp] = s1 * scl;
    }
}

// ============== main fused kernel: R16 + anode-in-registers (LDS 70 KiB -> 2 blocks/CU) ==============
__global__ __launch_bounds__(512, 2) void k_main(
    const float* __restrict__ Wih, const float* __restrict__ Whh,
    const float* __restrict__ Wd1, const float* __restrict__ bd1,
    const float* __restrict__ Wd2, const float* __restrict__ bd2,
    const float* __restrict__ anode, const float* __restrict__ S0,
    const float* __restrict__ S1, const float* __restrict__ xn,
    const float* __restrict__ shE0, float* __restrict__ out) {
    // LDS 70 KiB (lds_an removed)
    __shared__ u16   lds_wd1[64 * 256];     // [outcol][k'] bf16, 16-way swizzled, perm16 k
    __shared__ u16   lds_h0[2][16 * 128];   // [node][h''] bf16, 16-way swizzled, parity dbuf
    __shared__ u16   lds_h1[2][16 * 128];
    __shared__ u16   lds_c1[2][16 * 128];
    __shared__ u16   lds_d1[2][16 * 64];    // relu'd d1, 8-way swizzle (128B rows), dbuf
    __shared__ s16x8 lds_wd2f[128];         // Wd2 A-fragments [kt][lane]
    __shared__ float lds_s0[2][512];        // staged S0 (col' order, prescaled), parity dbuf
    __shared__ float lds_s1[2][512];        // staged S1

    const int tid = threadIdx.x;
    const int wave = tid >> 6, lane = tid & 63;
    const int lrow = lane & 15, lk = lane >> 4;
    const int blk = blockIdx.x;
    const int b = blk / BPG;
    const int nodeBase = blk * MB;

    // ---- persistent weight A-fragments (bf16), rows = col', perm16 k, GATE-PRESCALED ----
    s16x8 wb0[4][4], wb1[4][4], wb2[4][4];
    {
        const float scl = ((lrow & 3) == 2) ? TWO_LOG2E : -LOG2E;
#pragma unroll
        for (int nt = 0; nt < 4; nt++) {
            const int hcol = wave * 16 + nt * 4 + (lrow >> 2);
            const int colI = (lrow & 3) * 128 + hcol;
#pragma unroll
            for (int kt = 0; kt < 4; kt++) {
                s16x8 v0, v1, v2;
#pragma unroll
                for (int j = 0; j < 8; j++) {
                    int kp = kt * 32 + lk * 8 + j;                      // k' slot
                    int k = (kp & ~15) | ((kp & 3) << 2) | ((kp >> 2) & 3);  // physical h
                    v0[j] = (short)f2bf(Whh[colI * 128 + k] * scl);
                    float w1 = (k >= 125) ? 0.0f : Wih[65536 + colI * 128 + k];
                    v1[j] = (short)f2bf(w1 * scl);
                    v2[j] = (short)f2bf(Whh[65536 + colI * 128 + k] * scl);
                }
                wb0[nt][kt] = v0; wb1[nt][kt] = v1; wb2[nt][kt] = v2;
            }
        }
    }

    // ---- stage W_d1 -> LDS bf16, 16-way swizzle, perm16 k within each 128-half ----
    {
        int row = tid >> 3, k0 = (tid & 7) * 32;
#pragma unroll
        for (int i = 0; i < 4; i++) {
            s16x8 v;
#pragma unroll
            for (int j = 0; j < 8; j++) {
                int kp = k0 + i * 8 + j;          // 0..255
                int kin = kp & 127;
                int k = (kin & ~15) | ((kin & 3) << 2) | ((kin >> 2) & 3);
                v[j] = (short)f2bf(Wd1[row * 256 + (kp & 128) + k]);
            }
            int byte = (row * 512 + (k0 + i * 8) * 2) ^ ((row & 15) << 4);
            *(s16x8*)((char*)lds_wd1 + byte) = v;
        }
    }
    // ---- stage Wd2 A-fragments: A[row=o][k=outcol] (plain k, rows>=3 zero) ----
    if (tid < 128) {
        int kt = tid >> 6, ln = tid & 63;
        int rw = ln & 15, ks = kt * 32 + (ln >> 4) * 8;
        s16x8 v;
#pragma unroll
        for (int j = 0; j < 8; j++)
            v[j] = (rw < 3) ? (short)f2bf(Wd2[rw * 64 + ks + j]) : (short)0;
        lds_wd2f[tid] = v;
    }
    // ---- anode addend -> 16 persistent VGPRs (loop-invariant; prescaled at source) ----
    f32x4 anr[4];
    {
        const float* ap = anode + (size_t)blk * 8192 + lrow * 512 + wave * 64 + lk * 4;
#pragma unroll
        for (int nt = 0; nt < 4; nt++) anr[nt] = *(const f32x4*)(ap + nt * 16);
    }
    // ---- per-lane h-state write offset: node=lrow, slots (wave*16+lk*4)+nt, 16-way swz ----
    const int hwByte = (lrow * 256 + wave * 32 + lk * 8) ^ ((lrow & 15) << 4);
    // ---- init state: H0=C0=H1=C1 = x0 (true units; lane owns h = wave*16+nt*4+lk, node=lrow) ----
    float c0r[4], c1r[4];
    {
        float x0[4];
#pragma unroll
        for (int nt = 0; nt < 4; nt++) {
            int h = wave * 16 + nt * 4 + lk;
            x0[nt] = xn[(size_t)(nodeBase + lrow) * 128 + h] + shE0[b * 128 + h];
            c0r[nt] = x0[nt]; c1r[nt] = x0[nt];
        }
        u32x2 hv;
        hv[0] = cvt_pk_bf16(x0[0], x0[1]); hv[1] = cvt_pk_bf16(x0[2], x0[3]);
        *(u32x2*)((char*)lds_h0[1] + hwByte) = hv;
        *(u32x2*)((char*)lds_h1[1] + hwByte) = hv;
    }
    // ---- B-fragment read offsets, full-expression 16-way XOR (kt-resolved) ----
    int rdA4[4], wdA4[4];
    const int colD = (wave & 3) * 16 + lrow;
#pragma unroll
    for (int kt = 0; kt < 4; kt++) {
        rdA4[kt] = (lrow * 256 + kt * 64 + lk * 16) ^ ((lrow & 15) << 4);
        wdA4[kt] = (colD * 512 + kt * 64 + lk * 16) ^ ((colD & 15) << 4);  // +256 folds (bit 8 clear)
    }

    // decoder / out-phase per-lane preloads
    const f32x4 bd1i = *(const f32x4*)(bd1 + (wave & 3) * 16 + lk * 4);  // outcols wave*16+lk*4+r
    f32x4 bd2i;
#pragma unroll
    for (int r = 0; r < 4; r++)
        bd2i[r] = (lk == 0 && r < 3) ? bd2[r] : 0.f;

    const float* s0base = S0 + (size_t)b * 256 * 512 + wave * 64 + lane;
    const float* s1base = S1 + (size_t)b * 256 * 512 + wave * 64 + lane;
    // prologue: stage s0[0] -> parity 0 (consumed at t=-1)
    gload_lds4(s0base, &lds_s0[0][wave * 64]);
    __syncthreads();   // drains DMA (compiler emits vmcnt(0) before barrier)

    // incremental DMA pointers (no per-iter mul/clamp; harmless overrun stays inside ws)
    const float* s1dma = s1base;          // iter t loads s1[t+1]; first use at t=-1 -> s1[0]
    const float* s0dma = s0base + 512;    // iter t loads s0[t+2]; first use at t=-1 -> s0[1]

    float* outp = out + (size_t)nodeBase * (TDIM * 3);
    const int sRd = wave * 256 + lk * 16;   // + nt*64 : addend f32x4 (broadcast over lrow)

    // Pipeline: iter t does  out(t-2) | l1(t)+l0(t+1) fused | dec(t-1), 1 barrier.
#pragma unroll 1
    for (int t = -1; t < 258; ++t) {
        // ===== issue next-iteration S DMAs (in flight across this whole iter) =====
        gload_lds4(s1dma, &lds_s1[(t + 1) & 1][wave * 64]);
        gload_lds4(s0dma, &lds_s0[t & 1][wave * 64]);
        s1dma += 512; s0dma += 512;
        // ===== out(t-2): wave 4: D[o][node] = Wd2-frags x d1-frags; 12B/node stores =====
        if (t >= 2 && wave == 4) {
            const char* d1d = (const char*)lds_d1[t & 1];   // d1(t-2) parity = t&1
            f32x4 accO = bd2i;
#pragma unroll
            for (int kt = 0; kt < 2; kt++) {
                s16x8 bf = *(const s16x8*)(d1d + ((lrow * 128 + kt * 64 + lk * 16) ^ ((lrow & 7) << 4)));
                accO = __builtin_amdgcn_mfma_f32_16x16x32_bf16(lds_wd2f[kt * 64 + lane], bf, accO, 0, 0, 0);
            }
            if (lk == 0) {
#pragma unroll
                for (int r = 0; r < 3; r++)
                    outp[(size_t)lrow * (TDIM * 3) + (t - 2) * 3 + r] = accO[r];
            }
        }
        // ===== FAST PATH t in [0,255): fused l1(t)+l0(t+1), C-seeded accs =====
        if (t >= 0 && t < 255) {
            const char* h0rd = (const char*)lds_h0[t & 1];
            const char* h1rd = (const char*)lds_h1[(t + 1) & 1];   // == (t-1)&1
            s16x8 a0[4], a1[4];
#pragma unroll
            for (int kt = 0; kt < 4; kt++) {
                a0[kt] = *(const s16x8*)(h0rd + rdA4[kt]);
                a1[kt] = *(const s16x8*)(h1rd + rdA4[kt]);
            }
            // -- layer1 MFMAs, C-operand seeded with S1[t] (prescaled) --
            f32x4 acc[4];
            {
                const char* s1p = (const char*)lds_s1[t & 1];
#pragma unroll
                for (int nt = 0; nt < 4; nt++) acc[nt] = *(const f32x4*)(s1p + sRd + nt * 64);
            }
#pragma unroll
            for (int kt = 0; kt < 4; kt++) {
#pragma unroll
                for (int nt = 0; nt < 4; nt++)
                    acc[nt] = __builtin_amdgcn_mfma_f32_16x16x32_bf16(wb1[nt][kt], a0[kt], acc[nt], 0, 0, 0);
#pragma unroll
                for (int nt = 0; nt < 4; nt++)
                    acc[nt] = __builtin_amdgcn_mfma_f32_16x16x32_bf16(wb2[nt][kt], a1[kt], acc[nt], 0, 0, 0);
            }
            // -- layer1 eltwise + store (a1, acc die here; a0 stays live) --
            {
                float hf[4], cf[4];
#pragma unroll
                for (int nt = 0; nt < 4; nt++) {
                    float iv = sigmP(acc[nt][0]);
                    float fv = sigmP(acc[nt][1]);
                    float gv = tanhP(acc[nt][2]);
                    float ov = sigmP(acc[nt][3]);
                    float c = fv * c1r[nt] + iv * gv;
                    c1r[nt] = c;
                    cf[nt] = c;
                    hf[nt] = ov * tanhC(c);
                }
                u32x2 hv, cv;
                hv[0] = cvt_pk_bf16(hf[0], hf[1]); hv[1] = cvt_pk_bf16(hf[2], hf[3]);
                cv[0] = cvt_pk_bf16(cf[0], cf[1]); cv[1] = cvt_pk_bf16(cf[2], cf[3]);
                *(u32x2*)((char*)lds_h1[t & 1] + hwByte) = hv;
                *(u32x2*)((char*)lds_c1[t & 1] + hwByte) = cv;
            }
            // -- layer0 MFMAs reuse a0, C seeded with S0[t+1] (prescaled) --
            f32x4 acc0[4];
            {
                const char* s0p = (const char*)lds_s0[(t + 1) & 1];
#pragma unroll
                for (int nt = 0; nt < 4; nt++) acc0[nt] = *(const f32x4*)(s0p + sRd + nt * 64);
            }
#pragma unroll
            for (int kt = 0; kt < 4; kt++) {
#pragma unroll
                for (int nt = 0; nt < 4; nt++)
                    acc0[nt] = __builtin_amdgcn_mfma_f32_16x16x32_bf16(wb0[nt][kt], a0[kt], acc0[nt], 0, 0, 0);
            }
            // -- layer0 eltwise + store (anr addend from registers) --
            {
                float hf[4];
#pragma unroll
                for (int nt = 0; nt < 4; nt++) {
                    float iv = sigmP(acc0[nt][0] + anr[nt][0]);
                    float fv = sigmP(acc0[nt][1] + anr[nt][1]);
                    float gv = tanhP(acc0[nt][2] + anr[nt][2]);
                    float ov = sigmP(acc0[nt][3] + anr[nt][3]);
                    float c = fv * c0r[nt] + iv * gv;
                    c0r[nt] = c;
                    hf[nt] = ov * tanhC(c);
                }
                u32x2 hv;
                hv[0] = cvt_pk_bf16(hf[0], hf[1]); hv[1] = cvt_pk_bf16(hf[2], hf[3]);
                *(u32x2*)((char*)lds_h0[(t + 1) & 1] + hwByte) = hv;
            }
        } else {
            // ===== EDGE: t == 255 -> layer1 only =====
            if (t == 255) {
                const char* h0rd = (const char*)lds_h0[t & 1];
                const char* h1rd = (const char*)lds_h1[(t + 1) & 1];
                f32x4 acc[4];
                {
                    const char* s1p = (const char*)lds_s1[t & 1];
#pragma unroll
                    for (int nt = 0; nt < 4; nt++) acc[nt] = *(const f32x4*)(s1p + sRd + nt * 64);
                }
#pragma unroll
                for (int kt = 0; kt < 4; kt++) {
                    s16x8 a0 = *(const s16x8*)(h0rd + rdA4[kt]);
                    s16x8 a1 = *(const s16x8*)(h1rd + rdA4[kt]);
#pragma unroll
                    for (int nt = 0; nt < 4; nt++)
                        acc[nt] = __builtin_amdgcn_mfma_f32_16x16x32_bf16(wb1[nt][kt], a0, acc[nt], 0, 0, 0);
#pragma unroll
                    for (int nt = 0; nt < 4; nt++)
                        acc[nt] = __builtin_amdgcn_mfma_f32_16x16x32_bf16(wb2[nt][kt], a1, acc[nt], 0, 0, 0);
                }
                float hf[4], cf[4];
#pragma unroll
                for (int nt = 0; nt < 4; nt++) {
                    float iv = sigmP(acc[nt][0]);
                    float fv = sigmP(acc[nt][1]);
                    float gv = tanhP(acc[nt][2]);
                    float ov = sigmP(acc[nt][3]);
                    float c = fv * c1r[nt] + iv * gv;
                    c1r[nt] = c;
                    cf[nt] = c;
                    hf[nt] = ov * tanhC(c);
                }
                u32x2 hv, cv;
                hv[0] = cvt_pk_bf16(hf[0], hf[1]); hv[1] = cvt_pk_bf16(hf[2], hf[3]);
                cv[0] = cvt_pk_bf16(cf[0], cf[1]); cv[1] = cvt_pk_bf16(cf[2], cf[3]);
                *(u32x2*)((char*)lds_h1[t & 1] + hwByte) = hv;
                *(u32x2*)((char*)lds_c1[t & 1] + hwByte) = cv;
            }
            // ===== EDGE: t == -1 -> layer0 only =====
            if (t == -1) {
                const char* h0rd = (const char*)lds_h0[t & 1];
                f32x4 acc0[4];
                {
                    const char* s0p = (const char*)lds_s0[(t + 1) & 1];
#pragma unroll
                    for (int nt = 0; nt < 4; nt++) acc0[nt] = *(const f32x4*)(s0p + sRd + nt * 64);
                }
#pragma unroll
                for (int kt = 0; kt < 4; kt++) {
                    s16x8 a0 = *(const s16x8*)(h0rd + rdA4[kt]);
#pragma unroll
                    for (int nt = 0; nt < 4; nt++)
                        acc0[nt] = __builtin_amdgcn_mfma_f32_16x16x32_bf16(wb0[nt][kt], a0, acc0[nt], 0, 0, 0);
                }
                float hf[4];
#pragma unroll
                for (int nt = 0; nt < 4; nt++) {
                    float iv = sigmP(acc0[nt][0] + anr[nt][0]);
                    float fv = sigmP(acc0[nt][1] + anr[nt][1]);
                    float gv = tanhP(acc0[nt][2] + anr[nt][2]);
                    float ov = sigmP(acc0[nt][3] + anr[nt][3]);
                    float c = fv * c0r[nt] + iv * gv;
                    c0r[nt] = c;
                    hf[nt] = ov * tanhC(c);
                }
                u32x2 hv;
                hv[0] = cvt_pk_bf16(hf[0], hf[1]); hv[1] = cvt_pk_bf16(hf[2], hf[3]);
                *(u32x2*)((char*)lds_h0[(t + 1) & 1] + hwByte) = hv;
            }
        }
        // ===== decoder(t-1): d1^T = Wd1-frags x [h1|c1]-frags, relu -> lds_d1 (waves 0-3) =====
        if (t >= 1 && t < 257 && wave < 4) {
            const char* h1d = (const char*)lds_h1[(t + 1) & 1];   // == (t-1)&1
            const char* c1d = (const char*)lds_c1[(t + 1) & 1];
            f32x4 acc2 = bd1i;
#pragma unroll
            for (int kt = 0; kt < 4; kt++) {
                s16x8 bf = *(const s16x8*)(h1d + rdA4[kt]);
                s16x8 a = *(const s16x8*)((const char*)lds_wd1 + wdA4[kt]);
                acc2 = __builtin_amdgcn_mfma_f32_16x16x32_bf16(a, bf, acc2, 0, 0, 0);
            }
#pragma unroll
            for (int kt = 0; kt < 4; kt++) {
                s16x8 bf = *(const s16x8*)(c1d + rdA4[kt]);
                s16x8 a = *(const s16x8*)((const char*)lds_wd1 + (wdA4[kt] + 256));
                acc2 = __builtin_amdgcn_mfma_f32_16x16x32_bf16(a, bf, acc2, 0, 0, 0);
            }
            // lane holds d1 outcols wave*16 + lk*4 + r for node lrow -> one 8B write
            float d0 = acc2[0] > 0.f ? acc2[0] : 0.f;
            float d1 = acc2[1] > 0.f ? acc2[1] : 0.f;
            float d2 = acc2[2] > 0.f ? acc2[2] : 0.f;
            float d3 = acc2[3] > 0.f ? acc2[3] : 0.f;
            u32x2 dv;
            dv[0] = cvt_pk_bf16(d0, d1); dv[1] = cvt_pk_bf16(d2, d3);
            *(u32x2*)((char*)lds_d1[(t + 1) & 1] +
                      ((lrow * 128 + wave * 32 + lk * 8) ^ ((lrow & 7) << 4))) = dv;
        }
        __syncthreads();
    }
}

extern "C" void kernel_launch(void* const* d_in, const int* in_sizes, int n_in,
                              void* d_out, int out_size, void* d_ws, size_t ws_size,
                              hipStream_t stream) {
    const float* node = (const float*)d_in[0];
    // d_in[1] = ptr (int32) — layout is fixed arange*2000, handled analytically
    const float* lat  = (const float*)d_in[2];
    const float* gms  = (const float*)d_in[3];
    const float* Wenc = (const float*)d_in[4];
    const float* benc = (const float*)d_in[5];
    const float* Wih  = (const float*)d_in[6];
    const float* Whh  = (const float*)d_in[7];
    const float* bih  = (const float*)d_in[8];
    const float* bhh  = (const float*)d_in[9];
    const float* Wd1  = (const float*)d_in[10];
    const float* bd1  = (const float*)d_in[11];
    const float* Wd2  = (const float*)d_in[12];
    const float* bd2  = (const float*)d_in[13];

    float* ws    = (float*)d_ws;
    float* M2    = ws + OFF_M2;
    float* shE0  = ws + OFF_SHE0;
    float* xn    = ws + OFF_XN;
    float* S0    = ws + OFF_S0;
    float* S1    = ws + OFF_S1;
    float* anode = ws + OFF_AN;

    k_m2<<<1, 512, 0, stream>>>(Wenc, Wih, M2);
    k_anode<<<NBLK, 512, 0, stream>>>(node, M2, anode);
    k_xn<<<NBLK, 512, 0, stream>>>(node, Wenc, xn);
    k_shared<<<BSZ * TDIM, 256, 0, stream>>>(lat, gms, Wenc, benc, Wih, bih, bhh, S0, S1, shE0);
    k_main<<<NBLK, 512, 0, stream>>>(Wih, Whh, Wd1, bd1, Wd2, bd2,
                                     anode, S0, S1, xn, shE0, (float*)d_out);
}

// Round 19
// 13436.531 us; speedup vs baseline: 1.5952x; 1.5952x over previous
//
#include <hip/hip_runtime.h>
#include <hip/hip_bf16.h>

// ---------------- problem constants ----------------
#define NPG   2000
#define BSZ   32
#define NTOT  64000
#define TDIM  256
#define HD    128
#define G4    512
#define MB    16
#define BPG   125
#define NBLK  4000

#define LOG2E      1.44269504088896340736f
#define TWO_LOG2E  2.88539008177792681472f

typedef float  f32x4 __attribute__((ext_vector_type(4)));
typedef short  s16x8 __attribute__((ext_vector_type(8)));
typedef unsigned int u32x2 __attribute__((ext_vector_type(2)));
typedef unsigned short u16;

__device__ __forceinline__ u16 f2bf(float x) {   // round-nearest-even
    unsigned u = __float_as_uint(x);
    return (u16)((u + 0x7FFFu + ((u >> 16) & 1u)) >> 16);
}
// packed f32x2 -> bf16x2 (RNE), single HW instruction
__device__ __forceinline__ unsigned cvt_pk_bf16(float lo, float hi) {
    unsigned r;
    asm("v_cvt_pk_bf16_f32 %0, %1, %2" : "=v"(r) : "v"(lo), "v"(hi));
    return r;
}
__device__ __forceinline__ float fastrcp(float x) { return __builtin_amdgcn_rcpf(x); }
// raw 2^x through a COMPILER-VISIBLE intrinsic (hazard waits inserted properly).
#if __has_builtin(__builtin_amdgcn_exp2f)
__device__ __forceinline__ float ex2(float x) { return __builtin_amdgcn_exp2f(x); }
#else
__device__ __forceinline__ float ex2(float x) { return exp2f(x); }
#endif
// Gate pre-activations are pre-scaled at precompute time:
//   sigmoid rows (g in {0,1,3}): y = -log2e * x  -> sigm = rcp(1 + 2^y)
//   tanh rows    (g == 2):       y = 2log2e * x  -> tanh = 1 - 2*rcp(2^y + 1)
__device__ __forceinline__ float sigmP(float y) { return fastrcp(1.0f + ex2(y)); }
__device__ __forceinline__ float tanhP(float y) { return 1.0f - 2.0f * fastrcp(ex2(y) + 1.0f); }
__device__ __forceinline__ float tanhC(float c) { return tanhP(c * TWO_LOG2E); }   // c in true units

// async global->LDS DMA, 4B per lane, lds dest = uniform base + lane*4
__device__ __forceinline__ void gload_lds4(const float* g, float* l) {
    __builtin_amdgcn_global_load_lds(
        (const __attribute__((address_space(1))) void*)g,
        (__attribute__((address_space(3))) void*)l, 4, 0, 0);
}

// ---- permutations (R5-verified) ----
// gate-col interleave: col' = h*4 + g        (orig gate col = g*128 + h)
// OPERAND-SWAPPED MFMA: D = A(W) x B(h) -> D[col'][node]
//   lane (lrow, lk), acc[nt]: node = lrow, col' = (wave*4+nt)*16 + lk*4 + r
//   => reg r IS the gate index g; h = wave*16 + nt*4 + lk. No transpose needed.
// h-state slot perm16: slot = w*16 + l*4 + n <-> physical h = w*16 + n*4 + l
// GATE PRESCALE: rows g==2 scaled by +2log2e; rows g in {0,1,3} by -log2e.
//   Applied to W_hh0/W_ih1z/W_hh1 fragments, S0, S1, anode. xn/shE0 (h/c units) unscaled.
// LDS swizzle: 16-way ((row&15)<<4) on h-state/an/wd1; lds_d1 keeps 8-way (128B rows).
// NOTE (R18 lesson): anode MUST stay in LDS — +16 persistent VGPRs spills (register file
//   exactly full at 2 waves/SIMD); 2 blocks/CU unreachable (needs <=128 regs/wave).

// ---------------- ws layout (float offsets) ----------------
#define OFF_M2    0
#define OFF_SHE0  4096
#define OFF_XN    8192
#define OFF_S0    8200192
#define OFF_S1    12394496
#define OFF_AN    16588800

// ============== precompute: M2[j][col] = sum_h W_enc[h][j] * W_ih0[col][h] ==============
__global__ void k_m2(const float* __restrict__ Wenc, const float* __restrict__ Wih,
                     float* __restrict__ M2) {
    int col = threadIdx.x;  // 512
    float acc[6];
#pragma unroll
    for (int j = 0; j < 6; j++) acc[j] = 0.f;
    for (int h = 0; h < 128; h++) {
        float wv = Wih[col * 128 + h];
#pragma unroll
        for (int j = 0; j < 6; j++) acc[j] += Wenc[h * 137 + j] * wv;
    }
#pragma unroll
    for (int j = 0; j < 6; j++) M2[j * 512 + col] = acc[j];
}

// ============== precompute: anode[blk][node r][col'] (gate-col permuted, prescaled) ==============
__global__ void k_anode(const float* __restrict__ node, const float* __restrict__ M2,
                        float* __restrict__ anode) {
    int blk = blockIdx.x;
    int col = threadIdx.x;  // 512 (orig col = g*128+h)
    float m[6];
#pragma unroll
    for (int j = 0; j < 6; j++) m[j] = M2[j * 512 + col];
    int g = col >> 7;
    float scl = (g == 2) ? TWO_LOG2E : -LOG2E;
    int colp = (col & 127) * 4 + g;                // col' = h*4 + g
    float* dst = anode + (size_t)blk * 8192 + colp;
#pragma unroll
    for (int r = 0; r < 16; r++) {
        const float* np = node + (size_t)(blk * MB + r) * 6;
        float a = 0.f;
#pragma unroll
        for (int j = 0; j < 6; j++) a += np[j] * m[j];
        dst[r * 512] = a * scl;
    }
}

// ============== precompute: xn[n][h] = sum_j node[n][j] * W_enc[h][j] ==============
__global__ void k_xn(const float* __restrict__ node, const float* __restrict__ Wenc,
                     float* __restrict__ xn) {
    int blk = blockIdx.x;             // 4000
    int h = threadIdx.x & 127;
    int rr = threadIdx.x >> 7;        // 0..3
#pragma unroll
    for (int i = 0; i < 4; i++) {
        int r = rr + i * 4;
        int n = blk * MB + r;
        float a = 0.f;
#pragma unroll
        for (int j = 0; j < 6; j++) a += node[(size_t)n * 6 + j] * Wenc[h * 137 + j];
        xn[(size_t)n * 128 + h] = a;
    }
}

// ============== precompute: shared per-(b,t) terms S0, S1 (col' order, prescaled), shE0 ==============
__global__ void k_shared(const float* __restrict__ lat, const float* __restrict__ gms,
                         const float* __restrict__ Wenc, const float* __restrict__ benc,
                         const float* __restrict__ Wih, const float* __restrict__ bih,
                         const float* __restrict__ bhh,
                         float* __restrict__ S0, float* __restrict__ S1,
                         float* __restrict__ shE0) {
    int bt = blockIdx.x;             // 8192
    int b = bt >> 8, tt = bt & 255;
    __shared__ float she[128];
    int t = threadIdx.x;             // 256
    const float* latp = lat + (size_t)(b * 256 + tt) * 128;
    const float* gp = gms + (size_t)(b * 256 + tt) * 3;
    float g0 = gp[0], g1 = gp[1], g2 = gp[2];
    if (t < 128) {
        float a = benc[t];
        const float* we = Wenc + t * 137;
        for (int i = 0; i < 128; i++) a += latp[i] * we[6 + i];
        a += g0 * we[134] + g1 * we[135] + g2 * we[136];
        she[t] = a;
        if (tt == 0) shE0[b * 128 + t] = a;
    }
    __syncthreads();
    for (int col = t; col < 512; col += 256) {
        float a = bih[col] + bhh[col];
        const float* wr = Wih + col * 128;
        for (int h = 0; h < 128; h++) a += she[h] * wr[h];
        int g = col >> 7;
        float scl = (g == 2) ? TWO_LOG2E : -LOG2E;
        int colp = (col & 127) * 4 + g;            // col' = h*4 + g
        S0[(size_t)(b * 256 + tt) * 512 + colp] = a * scl;
        const float* w1 = Wih + 65536 + col * 128;
        float s1 = bih[512 + col] + bhh[512 + col] + g0 * w1[125] + g1 * w1[126] + g2 * w1[127];
        S1[(size_t)(b * 256 + tt) * 512 + colp] = s1 * scl;
    }
}

// ============== main fused kernel (R16 best): exp2 prescale + 16-way swizzle ==============
__global__ __launch_bounds__(512, 2) void k_main(
    const float* __restrict__ Wih, const float* __restrict__ Whh,
    const float* __restrict__ Wd1, const float* __restrict__ bd1,
    const float* __restrict__ Wd2, const float* __restrict__ bd2,
    const float* __restrict__ anode, const float* __restrict__ S0,
    const float* __restrict__ S1, const float* __restrict__ xn,
    const float* __restrict__ shE0, float* __restrict__ out) {
    // LDS ~102 KiB
    __shared__ u16   lds_wd1[64 * 256];     // [outcol][k'] bf16, 16-way swizzled, perm16 k
    __shared__ float lds_an[16 * 512];      // [node][col'] f32, 16-way swizzled, prescaled
    __shared__ u16   lds_h0[2][16 * 128];   // [node][h''] bf16, 16-way swizzled, parity dbuf
    __shared__ u16   lds_h1[2][16 * 128];
    __shared__ u16   lds_c1[2][16 * 128];
    __shared__ u16   lds_d1[2][16 * 64];    // relu'd d1, 8-way swizzle (128B rows), dbuf
    __shared__ s16x8 lds_wd2f[128];         // Wd2 A-fragments [kt][lane]
    __shared__ float lds_s0[2][512];        // staged S0 (col' order, prescaled), parity dbuf
    __shared__ float lds_s1[2][512];        // staged S1

    const int tid = threadIdx.x;
    const int wave = tid >> 6, lane = tid & 63;
    const int lrow = lane & 15, lk = lane >> 4;
    const int blk = blockIdx.x;
    const int b = blk / BPG;
    const int nodeBase = blk * MB;

    // ---- persistent weight A-fragments (bf16), rows = col', perm16 k, GATE-PRESCALED ----
    s16x8 wb0[4][4], wb1[4][4], wb2[4][4];
    {
        const float scl = ((lrow & 3) == 2) ? TWO_LOG2E : -LOG2E;
#pragma unroll
        for (int nt = 0; nt < 4; nt++) {
            const int hcol = wave * 16 + nt * 4 + (lrow >> 2);
            const int colI = (lrow & 3) * 128 + hcol;
#pragma unroll
            for (int kt = 0; kt < 4; kt++) {
                s16x8 v0, v1, v2;
#pragma unroll
                for (int j = 0; j < 8; j++) {
                    int kp = kt * 32 + lk * 8 + j;                      // k' slot
                    int k = (kp & ~15) | ((kp & 3) << 2) | ((kp >> 2) & 3);  // physical h
                    v0[j] = (short)f2bf(Whh[colI * 128 + k] * scl);
                    float w1 = (k >= 125) ? 0.0f : Wih[65536 + colI * 128 + k];
                    v1[j] = (short)f2bf(w1 * scl);
                    v2[j] = (short)f2bf(Whh[65536 + colI * 128 + k] * scl);
                }
                wb0[nt][kt] = v0; wb1[nt][kt] = v1; wb2[nt][kt] = v2;
            }
        }
    }

    // ---- stage W_d1 -> LDS bf16, 16-way swizzle, perm16 k within each 128-half ----
    {
        int row = tid >> 3, k0 = (tid & 7) * 32;
#pragma unroll
        for (int i = 0; i < 4; i++) {
            s16x8 v;
#pragma unroll
            for (int j = 0; j < 8; j++) {
                int kp = k0 + i * 8 + j;          // 0..255
                int kin = kp & 127;
                int k = (kin & ~15) | ((kin & 3) << 2) | ((kin >> 2) & 3);
                v[j] = (short)f2bf(Wd1[row * 256 + (kp & 128) + k]);
            }
            int byte = (row * 512 + (k0 + i * 8) * 2) ^ ((row & 15) << 4);
            *(s16x8*)((char*)lds_wd1 + byte) = v;
        }
    }
    // ---- stage Wd2 A-fragments: A[row=o][k=outcol] (plain k, rows>=3 zero) ----
    if (tid < 128) {
        int kt = tid >> 6, ln = tid & 63;
        int rw = ln & 15, ks = kt * 32 + (ln >> 4) * 8;
        s16x8 v;
#pragma unroll
        for (int j = 0; j < 8; j++)
            v[j] = (rw < 3) ? (short)f2bf(Wd2[rw * 64 + ks + j]) : (short)0;
        lds_wd2f[tid] = v;
    }
    // ---- stage A_node slice -> LDS f32, 16-way swizzle ([node][col'], prescaled at src) ----
    {
        int nd = tid >> 5, c0 = (tid & 31) * 4;
        const float* src = anode + (size_t)blk * 8192 + nd * 512;
#pragma unroll
        for (int i = 0; i < 4; i++) {
            int col0 = c0 + i * 128;
            f32x4 v = *(const f32x4*)(src + col0);
            int byte = (nd * 2048 + col0 * 4) ^ ((nd & 15) << 4);
            *(f32x4*)((char*)lds_an + byte) = v;
        }
    }
    // ---- per-lane h-state write offset: node=lrow, slots (wave*16+lk*4)+nt, 16-way swz ----
    const int hwByte = (lrow * 256 + wave * 32 + lk * 8) ^ ((lrow & 15) << 4);
    // ---- init state: H0=C0=H1=C1 = x0 (true units; lane owns h = wave*16+nt*4+lk, node=lrow) ----
    float c0r[4], c1r[4];
    {
        float x0[4];
#pragma unroll
        for (int nt = 0; nt < 4; nt++) {
            int h = wave * 16 + nt * 4 + lk;
            x0[nt] = xn[(size_t)(nodeBase + lrow) * 128 + h] + shE0[b * 128 + h];
            c0r[nt] = x0[nt]; c1r[nt] = x0[nt];
        }
        u32x2 hv;
        hv[0] = cvt_pk_bf16(x0[0], x0[1]); hv[1] = cvt_pk_bf16(x0[2], x0[3]);
        *(u32x2*)((char*)lds_h0[1] + hwByte) = hv;
        *(u32x2*)((char*)lds_h1[1] + hwByte) = hv;
    }
    // ---- B-fragment read offsets, full-expression 16-way XOR (kt-resolved) ----
    int rdA4[4], wdA4[4];
    const int colD = (wave & 3) * 16 + lrow;
#pragma unroll
    for (int kt = 0; kt < 4; kt++) {
        rdA4[kt] = (lrow * 256 + kt * 64 + lk * 16) ^ ((lrow & 15) << 4);
        wdA4[kt] = (colD * 512 + kt * 64 + lk * 16) ^ ((colD & 15) << 4);  // +256 folds (bit 8 clear)
    }

    // decoder / out-phase per-lane preloads
    const f32x4 bd1i = *(const f32x4*)(bd1 + (wave & 3) * 16 + lk * 4);  // outcols wave*16+lk*4+r
    f32x4 bd2i;
#pragma unroll
    for (int r = 0; r < 4; r++)
        bd2i[r] = (lk == 0 && r < 3) ? bd2[r] : 0.f;

    const float* s0base = S0 + (size_t)b * 256 * 512 + wave * 64 + lane;
    const float* s1base = S1 + (size_t)b * 256 * 512 + wave * 64 + lane;
    // prologue: stage s0[0] -> parity 0 (consumed at t=-1)
    gload_lds4(s0base, &lds_s0[0][wave * 64]);
    __syncthreads();   // drains DMA (compiler emits vmcnt(0) before barrier)

    // incremental DMA pointers (no per-iter mul/clamp; harmless overrun stays inside ws)
    const float* s1dma = s1base;          // iter t loads s1[t+1]; first use at t=-1 -> s1[0]
    const float* s0dma = s0base + 512;    // iter t loads s0[t+2]; first use at t=-1 -> s0[1]

    float* outp = out + (size_t)nodeBase * (TDIM * 3);
    const int sRd = wave * 256 + lk * 16;   // + nt*64 : addend f32x4 (broadcast over lrow)
    // an read: FULL-expression 16-way XOR per nt (loop-invariant)
    int anA[4];
#pragma unroll
    for (int nt = 0; nt < 4; nt++)
        anA[nt] = (lrow * 2048 + wave * 256 + nt * 64 + lk * 16) ^ ((lrow & 15) << 4);

    // Pipeline: iter t does  out(t-2) | l1(t)+l0(t+1) fused | dec(t-1), 1 barrier.
#pragma unroll 1
    for (int t = -1; t < 258; ++t) {
        // ===== issue next-iteration S DMAs (in flight across this whole iter) =====
        gload_lds4(s1dma, &lds_s1[(t + 1) & 1][wave * 64]);
        gload_lds4(s0dma, &lds_s0[t & 1][wave * 64]);
        s1dma += 512; s0dma += 512;
        // ===== out(t-2): wave 4: D[o][node] = Wd2-frags x d1-frags; 12B/node stores =====
        if (t >= 2 && wave == 4) {
            const char* d1d = (const char*)lds_d1[t & 1];   // d1(t-2) parity = t&1
            f32x4 accO = bd2i;
#pragma unroll
            for (int kt = 0; kt < 2; kt++) {
                s16x8 bf = *(const s16x8*)(d1d + ((lrow * 128 + kt * 64 + lk * 16) ^ ((lrow & 7) << 4)));
                accO = __builtin_amdgcn_mfma_f32_16x16x32_bf16(lds_wd2f[kt * 64 + lane], bf, accO, 0, 0, 0);
            }
            if (lk == 0) {
#pragma unroll
                for (int r = 0; r < 3; r++)
                    outp[(size_t)lrow * (TDIM * 3) + (t - 2) * 3 + r] = accO[r];
            }
        }
        // ===== FAST PATH t in [0,255): fused l1(t)+l0(t+1), C-seeded accs =====
        if (t >= 0 && t < 255) {
            const char* h0rd = (const char*)lds_h0[t & 1];
            const char* h1rd = (const char*)lds_h1[(t + 1) & 1];   // == (t-1)&1
            s16x8 a0[4], a1[4];
#pragma unroll
            for (int kt = 0; kt < 4; kt++) {
                a0[kt] = *(const s16x8*)(h0rd + rdA4[kt]);
                a1[kt] = *(const s16x8*)(h1rd + rdA4[kt]);
            }
            // -- layer1 MFMAs, C-operand seeded with S1[t] (prescaled) --
            f32x4 acc[4];
            {
                const char* s1p = (const char*)lds_s1[t & 1];
#pragma unroll
                for (int nt = 0; nt < 4; nt++) acc[nt] = *(const f32x4*)(s1p + sRd + nt * 64);
            }
#pragma unroll
            for (int kt = 0; kt < 4; kt++) {
#pragma unroll
                for (int nt = 0; nt < 4; nt++)
                    acc[nt] = __builtin_amdgcn_mfma_f32_16x16x32_bf16(wb1[nt][kt], a0[kt], acc[nt], 0, 0, 0);
#pragma unroll
                for (int nt = 0; nt < 4; nt++)
                    acc[nt] = __builtin_amdgcn_mfma_f32_16x16x32_bf16(wb2[nt][kt], a1[kt], acc[nt], 0, 0, 0);
            }
            // -- layer1 eltwise + store (a1, acc die here; a0 stays live) --
            {
                float hf[4], cf[4];
#pragma unroll
                for (int nt = 0; nt < 4; nt++) {
                    float iv = sigmP(acc[nt][0]);
                    float fv = sigmP(acc[nt][1]);
                    float gv = tanhP(acc[nt][2]);
                    float ov = sigmP(acc[nt][3]);
                    float c = fv * c1r[nt] + iv * gv;
                    c1r[nt] = c;
                    cf[nt] = c;
                    hf[nt] = ov * tanhC(c);
                }
                u32x2 hv, cv;
                hv[0] = cvt_pk_bf16(hf[0], hf[1]); hv[1] = cvt_pk_bf16(hf[2], hf[3]);
                cv[0] = cvt_pk_bf16(cf[0], cf[1]); cv[1] = cvt_pk_bf16(cf[2], cf[3]);
                *(u32x2*)((char*)lds_h1[t & 1] + hwByte) = hv;
                *(u32x2*)((char*)lds_c1[t & 1] + hwByte) = cv;
            }
            // -- layer0 MFMAs reuse a0, C seeded with S0[t+1] (prescaled) --
            f32x4 acc0[4];
            {
                const char* s0p = (const char*)lds_s0[(t + 1) & 1];
#pragma unroll
                for (int nt = 0; nt < 4; nt++) acc0[nt] = *(const f32x4*)(s0p + sRd + nt * 64);
            }
#pragma unroll
            for (int kt = 0; kt < 4; kt++) {
#pragma unroll
                for (int nt = 0; nt < 4; nt++)
                    acc0[nt] = __builtin_amdgcn_mfma_f32_16x16x32_bf16(wb0[nt][kt], a0[kt], acc0[nt], 0, 0, 0);
            }
            // -- layer0 eltwise + store --
            {
                float hf[4];
                const char* anp = (const char*)lds_an;
#pragma unroll
                for (int nt = 0; nt < 4; nt++) {
                    f32x4 an = *(const f32x4*)(anp + anA[nt]);
                    float iv = sigmP(acc0[nt][0] + an[0]);
                    float fv = sigmP(acc0[nt][1] + an[1]);
                    float gv = tanhP(acc0[nt][2] + an[2]);
                    float ov = sigmP(acc0[nt][3] + an[3]);
                    float c = fv * c0r[nt] + iv * gv;
                    c0r[nt] = c;
                    hf[nt] = ov * tanhC(c);
                }
                u32x2 hv;
                hv[0] = cvt_pk_bf16(hf[0], hf[1]); hv[1] = cvt_pk_bf16(hf[2], hf[3]);
                *(u32x2*)((char*)lds_h0[(t + 1) & 1] + hwByte) = hv;
            }
        } else {
            // ===== EDGE: t == 255 -> layer1 only =====
            if (t == 255) {
                const char* h0rd = (const char*)lds_h0[t & 1];
                const char* h1rd = (const char*)lds_h1[(t + 1) & 1];
                f32x4 acc[4];
                {
                    const char* s1p = (const char*)lds_s1[t & 1];
#pragma unroll
                    for (int nt = 0; nt < 4; nt++) acc[nt] = *(const f32x4*)(s1p + sRd + nt * 64);
                }
#pragma unroll
                for (int kt = 0; kt < 4; kt++) {
                    s16x8 a0 = *(const s16x8*)(h0rd + rdA4[kt]);
                    s16x8 a1 = *(const s16x8*)(h1rd + rdA4[kt]);
#pragma unroll
                    for (int nt = 0; nt < 4; nt++)
                        acc[nt] = __builtin_amdgcn_mfma_f32_16x16x32_bf16(wb1[nt][kt], a0, acc[nt], 0, 0, 0);
#pragma unroll
                    for (int nt = 0; nt < 4; nt++)
                        acc[nt] = __builtin_amdgcn_mfma_f32_16x16x32_bf16(wb2[nt][kt], a1, acc[nt], 0, 0, 0);
                }
                float hf[4], cf[4];
#pragma unroll
                for (int nt = 0; nt < 4; nt++) {
                    float iv = sigmP(acc[nt][0]);
                    float fv = sigmP(acc[nt][1]);
                    float gv = tanhP(acc[nt][2]);
                    float ov = sigmP(acc[nt][3]);
                    float c = fv * c1r[nt] + iv * gv;
                    c1r[nt] = c;
                    cf[nt] = c;
                    hf[nt] = ov * tanhC(c);
                }
                u32x2 hv, cv;
                hv[0] = cvt_pk_bf16(hf[0], hf[1]); hv[1] = cvt_pk_bf16(hf[2], hf[3]);
                cv[0] = cvt_pk_bf16(cf[0], cf[1]); cv[1] = cvt_pk_bf16(cf[2], cf[3]);
                *(u32x2*)((char*)lds_h1[t & 1] + hwByte) = hv;
                *(u32x2*)((char*)lds_c1[t & 1] + hwByte) = cv;
            }
            // ===== EDGE: t == -1 -> layer0 only =====
            if (t == -1) {
                const char* h0rd = (const char*)lds_h0[t & 1];
                f32x4 acc0[4];
                {
                    const char* s0p = (const char*)lds_s0[(t + 1) & 1];
#pragma unroll
                    for (int nt = 0; nt < 4; nt++) acc0[nt] = *(const f32x4*)(s0p + sRd + nt * 64);
                }
#pragma unroll
                for (int kt = 0; kt < 4; kt++) {
                    s16x8 a0 = *(const s16x8*)(h0rd + rdA4[kt]);
#pragma unroll
                    for (int nt = 0; nt < 4; nt++)
                        acc0[nt] = __builtin_amdgcn_mfma_f32_16x16x32_bf16(wb0[nt][kt], a0, acc0[nt], 0, 0, 0);
                }
                float hf[4];
                const char* anp = (const char*)lds_an;
#pragma unroll
                for (int nt = 0; nt < 4; nt++) {
                    f32x4 an = *(const f32x4*)(anp + anA[nt]);
                    float iv = sigmP(acc0[nt][0] + an[0]);
                    float fv = sigmP(acc0[nt][1] + an[1]);
                    float gv = tanhP(acc0[nt][2] + an[2]);
                    float ov = sigmP(acc0[nt][3] + an[3]);
                    float c = fv * c0r[nt] + iv * gv;
                    c0r[nt] = c;
                    hf[nt] = ov * tanhC(c);
                }
                u32x2 hv;
                hv[0] = cvt_pk_bf16(hf[0], hf[1]); hv[1] = cvt_pk_bf16(hf[2], hf[3]);
                *(u32x2*)((char*)lds_h0[(t + 1) & 1] + hwByte) = hv;
            }
        }
        // ===== decoder(t-1): d1^T = Wd1-frags x [h1|c1]-frags, relu -> lds_d1 (waves 0-3) =====
        if (t >= 1 && t < 257 && wave < 4) {
            const char* h1d = (const char*)lds_h1[(t + 1) & 1];   // == (t-1)&1
            const char* c1d = (const char*)lds_c1[(t + 1) & 1];
            f32x4 acc2 = bd1i;
#pragma unroll
            for (int kt = 0; kt < 4; kt++) {
                s16x8 bf = *(const s16x8*)(h1d + rdA4[kt]);
                s16x8 a = *(const s16x8*)((const char*)lds_wd1 + wdA4[kt]);
                acc2 = __builtin_amdgcn_mfma_f32_16x16x32_bf16(a, bf, acc2, 0, 0, 0);
            }
#pragma unroll
            for (int kt = 0; kt < 4; kt++) {
                s16x8 bf = *(const s16x8*)(c1d + rdA4[kt]);
                s16x8 a = *(const s16x8*)((const char*)lds_wd1 + (wdA4[kt] + 256));
                acc2 = __builtin_amdgcn_mfma_f32_16x16x32_bf16(a, bf, acc2, 0, 0, 0);
            }
            // lane holds d1 outcols wave*16 + lk*4 + r for node lrow -> one 8B write
            float d0 = acc2[0] > 0.f ? acc2[0] : 0.f;
            float d1 = acc2[1] > 0.f ? acc2[1] : 0.f;
            float d2 = acc2[2] > 0.f ? acc2[2] : 0.f;
            float d3 = acc2[3] > 0.f ? acc2[3] : 0.f;
            u32x2 dv;
            dv[0] = cvt_pk_bf16(d0, d1); dv[1] = cvt_pk_bf16(d2, d3);
            *(u32x2*)((char*)lds_d1[(t + 1) & 1] +
                      ((lrow * 128 + wave * 32 + lk * 8) ^ ((lrow & 7) << 4))) = dv;
        }
        __syncthreads();
    }
}

extern "C" void kernel_launch(void* const* d_in, const int* in_sizes, int n_in,
                              void* d_out, int out_size, void* d_ws, size_t ws_size,
                              hipStream_t stream) {
    const float* node = (const float*)d_in[0];
    // d_in[1] = ptr (int32) — layout is fixed arange*2000, handled analytically
    const float* lat  = (const float*)d_in[2];
    const float* gms  = (const float*)d_in[3];
    const float* Wenc = (const float*)d_in[4];
    const float* benc = (const float*)d_in[5];
    const float* Wih  = (const float*)d_in[6];
    const float* Whh  = (const float*)d_in[7];
    const float* bih  = (const float*)d_in[8];
    const float* bhh  = (const float*)d_in[9];
    const float* Wd1  = (const float*)d_in[10];
    const float* bd1  = (const float*)d_in[11];
    const float* Wd2  = (const float*)d_in[12];
    const float* bd2  = (const float*)d_in[13];

    float* ws    = (float*)d_ws;
    float* M2    = ws + OFF_M2;
    float* shE0  = ws + OFF_SHE0;
    float* xn    = ws + OFF_XN;
    float* S0    = ws + OFF_S0;
    float* S1    = ws + OFF_S1;
    float* anode = ws + OFF_AN;

    k_m2<<<1, 512, 0, stream>>>(Wenc, Wih, M2);
    k_anode<<<NBLK, 512, 0, stream>>>(node, M2, anode);
    k_xn<<<NBLK, 512, 0, stream>>>(node, Wenc, xn);
    k_shared<<<BSZ * TDIM, 256, 0, stream>>>(lat, gms, Wenc, benc, Wih, bih, bhh, S0, S1, shE0);
    k_main<<<NBLK, 512, 0, stream>>>(Wih, Whh, Wd1, bd1, Wd2, bd2,
                                     anode, S0, S1, xn, shE0, (float*)d_out);
}